// Round 16
// baseline (552.716 us; speedup 1.0000x reference)
//
#include <hip/hip_runtime.h>

typedef _Float16 f16;
typedef _Float16 f16x8 __attribute__((ext_vector_type(8)));
typedef _Float16 f16x4 __attribute__((ext_vector_type(4)));
typedef __fp16 fp16x2 __attribute__((ext_vector_type(2)));
typedef float f32x4 __attribute__((ext_vector_type(4)));

#define NTOK 49
#define NH 16
#define HD 32
#define DIM 512
#define NWIN 64
#define NB 2048
#define MTOT (NB*NTOK)      // 100352
#define SCALE 0.17677669529663687f
#define VTS 56              // vt t-stride (padded, 16B-aligned rows)

__device__ __forceinline__ void gload_lds16(const f16* g, f16* l) {
    __builtin_amdgcn_global_load_lds((const __attribute__((address_space(1))) void*)g,
                                     (__attribute__((address_space(3))) void*)l, 16, 0, 0);
}

// ---------------- convert fp32 -> fp16 (vectorized) ----------------
__device__ __forceinline__ void cvt_body(const float* __restrict__ s, f16* __restrict__ d,
                                         int n4, int bid, int nb) {
    int i = bid * 256 + threadIdx.x;
    int st = nb * 256;
    for (; i < n4; i += st) {
        float4 v = ((const float4*)s)[i];
        f16x4 o = { (f16)v.x, (f16)v.y, (f16)v.z, (f16)v.w };
        *(f16x4*)(d + (size_t)i * 4) = o;
    }
}

// ---- prep kernel: biasT/maskT fragment tables + x/qkv_w/proj_w converts ----
__global__ __launch_bounds__(256) void prep_kernel(const float* __restrict__ rpb,
                                                   const float* __restrict__ mask,
                                                   f16* __restrict__ biasT,
                                                   f16* __restrict__ maskT,
                                                   const float* __restrict__ qkvw,
                                                   f16* __restrict__ w16,
                                                   const float* __restrict__ projw,
                                                   f16* __restrict__ pw16,
                                                   const float* __restrict__ x,
                                                   f16* __restrict__ x16) {
    const int bid = blockIdx.x;
    if (bid >= 1280) {
        if (bid < 1280 + 2048)      cvt_body(x, x16, MTOT * DIM / 4, bid - 1280, 2048);
        else if (bid < 1280 + 2816) cvt_body(qkvw, w16, 1536 * 512 / 4, bid - 1280 - 2048, 768);
        else                        cvt_body(projw, pw16, 512 * 512 / 4, bid - 1280 - 2816, 256);
        return;
    }
    const bool isBias = (bid < 256);
    int idx = (isBias ? bid : bid - 256) * 256 + threadIdx.x;
    int r  = idx & 3;
    int j  = (idx >> 2) & 3;
    int i  = (idx >> 4) & 3;
    int l  = (idx >> 6) & 63;
    int wh = idx >> 12;             // h (0..15) or w (0..63)
    int g = l >> 4, c16 = l & 15;
    int k = i * 16 + g * 4 + r;     // k token
    int q = j * 16 + c16;           // q token
    float v;
    if (isBias) {
        if (k >= NTOK)      v = -30000.f;
        else if (q >= NTOK) v = 0.f;
        else {
            int rq = q / 7, cq = q - rq * 7;
            int rk = k / 7, ck = k - rk * 7;
            int rel = (rq - rk + 6) * 13 + (cq - ck + 6);
            v = rpb[rel * NH + wh];
        }
        biasT[idx] = (f16)v;
    } else {
        v = (k < NTOK && q < NTOK) ? mask[(wh * NTOK + q) * NTOK + k] : 0.f;
        maskT[idx] = (f16)v;
    }
}

#define WAIT_LGKM  asm volatile("s_waitcnt lgkmcnt(0)" ::: "memory")
#define WAIT_VM(N) asm volatile("s_waitcnt vmcnt(" #N ")" ::: "memory")

// ---------------- 256x256 GEMM (QKV), register-double-buffered k-half pipeline ----------------
template<int NT>   // NT = N/256 tiles
__global__ __launch_bounds__(512) void gemm256(const f16* __restrict__ A,
                                               const f16* __restrict__ Bw,
                                               const float* __restrict__ bias,
                                               f16* __restrict__ qo,
                                               f16* __restrict__ ko,
                                               f16* __restrict__ vto) {
    __shared__ __align__(16) f16 As[2][256][64];
    __shared__ __align__(16) f16 Bs[2][256][64];

    const int tid = threadIdx.x;
    const int lane = tid & 63;
    const int wv = tid >> 6;                 // 0..7
    const int wm = wv >> 2, wn = wv & 3;     // 2M x 4N wave grid
    const int g = lane >> 4, c16 = lane & 15;

    const int nblk = gridDim.x;
    const int f = blockIdx.x;
    const int work = (f & 7) * (nblk >> 3) + (f >> 3);
    const int m0 = (work / NT) * 256;
    const int n0 = (work % NT) * 256;

    const int srow = lane >> 3;
    const int schunk = (lane & 7) ^ srow;
    const f16* gA = A  + (size_t)(m0 + wv * 16 + srow) * DIM + schunk * 8;
    const f16* gB = Bw + (size_t)(n0 + wv * 16 + srow) * DIM + schunk * 8;

#define STAGE1(buf, kt, role) do {                                             \
    const f16* _s = (((role) < 2) ? gA : gB) + (size_t)(((role) & 1) * 128) * DIM + (kt) * 64; \
    f16* _d = ((role) < 2) ? &As[buf][((role) & 1) * 128 + wv * 16][0]         \
                           : &Bs[buf][((role) & 1) * 128 + wv * 16][0];        \
    gload_lds16(_s, _d);                                                       \
    gload_lds16(_s + (size_t)8 * DIM, _d + 8 * 64);                            \
} while (0)
#define STAGE_T(buf, kt) do { STAGE1(buf, kt, 0); STAGE1(buf, kt, 1);          \
                              STAGE1(buf, kt, 2); STAGE1(buf, kt, 3); } while (0)

#define READS(buf, kk, AF, BF) do {                                            \
    _Pragma("unroll") for (int _i = 0; _i < 8; ++_i)                           \
        (AF)[_i] = *(const f16x8*)&As[buf][wm * 128 + _i * 16 + c16][(((kk) * 4 + g) ^ (c16 & 7)) * 8]; \
    _Pragma("unroll") for (int _j = 0; _j < 4; ++_j)                           \
        (BF)[_j] = *(const f16x8*)&Bs[buf][wn * 64 + _j * 16 + c16][(((kk) * 4 + g) ^ (c16 & 7)) * 8]; \
} while (0)

#define MM(AF, BF) do {                                                        \
    __builtin_amdgcn_s_setprio(1);                                             \
    _Pragma("unroll") for (int _j = 0; _j < 4; ++_j)                           \
    _Pragma("unroll") for (int _i = 0; _i < 8; ++_i)                           \
        acc[_j][_i] = __builtin_amdgcn_mfma_f32_16x16x32_f16((BF)[_j], (AF)[_i], acc[_j][_i], 0, 0, 0); \
    __builtin_amdgcn_s_setprio(0);                                             \
} while (0)

    f32x4 acc[4][8];
#pragma unroll
    for (int j = 0; j < 4; ++j)
#pragma unroll
        for (int i = 0; i < 8; ++i)
            acc[j][i] = (f32x4){0.f, 0.f, 0.f, 0.f};

    f16x8 a0[8], b0[4], a1[8], b1[4];

    const int KT = DIM / 64;   // 8 K-tiles

    STAGE_T(0, 0);
    STAGE_T(1, 1);
    WAIT_VM(8);
    __builtin_amdgcn_s_barrier();
    READS(0, 0, a0, b0);

#pragma unroll
    for (int t = 0; t < KT; ++t) {
        const int b = t & 1, nb = b ^ 1;

        READS(b, 1, a1, b1);
        MM(a0, b0);
        WAIT_LGKM;
        __builtin_amdgcn_s_barrier();
        if (t + 2 < KT) STAGE_T(b, t + 2);
        if (t + 2 < KT) { WAIT_VM(8); }
        else if (t + 1 < KT) { WAIT_VM(0); }

        if (t + 1 < KT) READS(nb, 0, a0, b0);
        MM(a1, b1);
    }
#undef STAGE1
#undef STAGE_T
#undef READS
#undef MM

#pragma unroll
    for (int i = 0; i < 8; ++i) {
        const int m = m0 + wm * 128 + i * 16 + c16;
        const int bb = m / NTOK, tk = m - (m / NTOK) * NTOK;
#pragma unroll
        for (int j = 0; j < 4; ++j) {
            const int n = n0 + wn * 64 + j * 16 + g * 4;
            f32x4 v = acc[j][i];
            const f32x4 b4 = *(const f32x4*)&bias[n];
            v += b4;
            const int s = n >> 9;
            const int hh = (n >> 5) & 15;
            const int d0 = n & 31;
            const size_t bh = (size_t)(bb * NH + hh);
            if (s == 0) {
                f16x4 o = { (f16)(v[0] * SCALE), (f16)(v[1] * SCALE),
                            (f16)(v[2] * SCALE), (f16)(v[3] * SCALE) };
                *(f16x4*)(qo + (bh * NTOK + tk) * HD + d0) = o;
            } else if (s == 1) {
                f16x4 o = { (f16)v[0], (f16)v[1], (f16)v[2], (f16)v[3] };
                *(f16x4*)(ko + (bh * NTOK + tk) * HD + d0) = o;
            } else {
#pragma unroll
                for (int r = 0; r < 4; ++r)
                    vto[(bh * HD + d0 + r) * VTS + tk] = (f16)v[r];
            }
        }
    }
}

// ---------------- fused attention + output projection ----------------
// 1 block = 1 window b (2048 blocks, 1024 threads = 16 waves = 16 heads).
// Phase 1 (per wave h, independent): v4 attention -> O2 regs (normalized).
// Phase 2: barrier; O2 -> act LDS [64][512] f16 (chunk ^= row&7 swizzle),
//          rows 49..63 zeroed; barrier.
// Phase 3: proj C^T per wave: n-slice [h*32,h*32+32), 16 k-steps x
//          {4 ds_read_b128 af (swizzled) | 2 pw16 loads bf (L2-hot) | 8 MFMA};
//          float4 epilogue (m<49) straight to fp32 out.
// Kills the 206MB aout HBM round-trip + proj kernel tail. LDS: Ps(147KB)/act(64KB) aliased.
__global__ __launch_bounds__(1024, 4) void attn_proj_kernel(const f16* __restrict__ qw,
                                                            const f16* __restrict__ kw,
                                                            const f16* __restrict__ vt,
                                                            const f16* __restrict__ biasT,
                                                            const f16* __restrict__ maskT,
                                                            const f16* __restrict__ pw16,
                                                            const float* __restrict__ projb,
                                                            float* __restrict__ outp) {
    __shared__ __align__(16) f16 Ps[16][64][72];   // 147456 B; act[64][512] aliases the front 64KB
    f16* act = &Ps[0][0][0];

    const int h = threadIdx.x >> 6;   // wave = head
    const int l = threadIdx.x & 63;
    const int f = blockIdx.x;
    const int b = (f & 7) * (gridDim.x >> 3) + (f >> 3);   // window index (XCD-chunked)
    const int w = b & (NWIN - 1);
    const int g = l >> 4, c16 = l & 15;
    const int bid = b * NH + h;
    const size_t qkbase = (size_t)bid * (NTOK * HD);
    const size_t vbase = (size_t)bid * (HD * VTS);

    const f16x8 z8 = {};

    // ---- phase 1: attention (v4) ----
    // table-first order keeps peak VGPR ~(St 64 + qf/kf 32 + addr) < 128
    const f16* cbB = biasT + (((size_t)h * 64 + l) << 6);
    const f16* cbM = maskT + (((size_t)w * 64 + l) << 6);
    f32x4 St[4][4];
    {
        f16x8 cbv[8];
#pragma unroll
        for (int k = 0; k < 8; ++k)
            cbv[k] = *(const f16x8*)(cbB + k * 8) + *(const f16x8*)(cbM + k * 8);
#pragma unroll
        for (int i = 0; i < 4; ++i)
#pragma unroll
            for (int j = 0; j < 4; ++j) {
                const int e = i * 16 + j * 4;
#pragma unroll
                for (int r = 0; r < 4; ++r)
                    St[i][j][r] = (float)cbv[(e + r) >> 3][(e + r) & 7];
            }
    }
    {
        f16x8 qf[4], kf[4];
#pragma unroll
        for (int t = 0; t < 4; ++t) {
            int row = t * 16 + c16;
            f16x8 q = z8, k = z8;
            if (row < NTOK) {
                q = *(const f16x8*)(qw + qkbase + row * HD + g * 8);
                k = *(const f16x8*)(kw + qkbase + row * HD + g * 8);
            }
            qf[t] = q; kf[t] = k;
        }
#pragma unroll
        for (int i = 0; i < 4; ++i)
#pragma unroll
            for (int j = 0; j < 4; ++j)
                St[i][j] = __builtin_amdgcn_mfma_f32_16x16x32_f16(kf[i], qf[j], St[i][j], 0, 0, 0);
    }

    // prefetch V^T fragments (latency hides under softmax)
    f16x8 vfp[2][2];
#pragma unroll
    for (int c = 0; c < 2; ++c) {
        int tcol = c * 32 + g * 8;
#pragma unroll
        for (int td = 0; td < 2; ++td) {
            f16x8 vv = z8;
            if (tcol < VTS)
                vv = *(const f16x8*)(vt + vbase + (size_t)(td * 16 + c16) * VTS + tcol);
            vfp[c][td] = vv;
        }
    }

    // in-lane softmax per q-tile j
    float inv[4];
#pragma unroll
    for (int j = 0; j < 4; ++j) {
        float m = St[0][j][0];
#pragma unroll
        for (int i = 0; i < 4; ++i)
#pragma unroll
            for (int r = 0; r < 4; ++r) m = fmaxf(m, St[i][j][r]);
        m = fmaxf(m, __shfl_xor(m, 16, 64));
        m = fmaxf(m, __shfl_xor(m, 32, 64));
        float s = 0.f;
#pragma unroll
        for (int i = 0; i < 4; ++i)
#pragma unroll
            for (int r = 0; r < 4; ++r) {
                float p = __expf(St[i][j][r] - m);
                St[i][j][r] = p;
                s += p;
            }
        s += __shfl_xor(s, 16, 64);
        s += __shfl_xor(s, 32, 64);
        inv[j] = 1.f / s;
    }

    // pack P (unnormalized), wave-private Ps slice
#pragma unroll
    for (int j = 0; j < 4; ++j) {
        const int q = j * 16 + c16;
#pragma unroll
        for (int i = 0; i < 4; ++i) {
            fp16x2 u0 = __builtin_amdgcn_cvt_pkrtz(St[i][j][0], St[i][j][1]);
            fp16x2 u1 = __builtin_amdgcn_cvt_pkrtz(St[i][j][2], St[i][j][3]);
            *(fp16x2*)&Ps[h][q][i * 16 + 4 * g]     = u0;
            *(fp16x2*)&Ps[h][q][i * 16 + 4 * g + 2] = u1;
        }
    }
    WAIT_LGKM;   // wave-private: write->read ordering only

    f32x4 O2[2][4];
    const f32x4 zf = (f32x4){0.f, 0.f, 0.f, 0.f};
#pragma unroll
    for (int td = 0; td < 2; ++td)
#pragma unroll
        for (int ti = 0; ti < 4; ++ti) O2[td][ti] = zf;
#pragma unroll
    for (int c = 0; c < 2; ++c) {
        f16x8 pf[4];
#pragma unroll
        for (int ti = 0; ti < 4; ++ti)
            pf[ti] = *(const f16x8*)&Ps[h][ti * 16 + c16][c * 32 + g * 8];
#pragma unroll
        for (int td = 0; td < 2; ++td)
#pragma unroll
            for (int ti = 0; ti < 4; ++ti)
                O2[td][ti] = __builtin_amdgcn_mfma_f32_16x16x32_f16(vfp[c][td], pf[ti], O2[td][ti], 0, 0, 0);
    }

    // ---- phase 2: all PV done -> overlay act onto Ps ----
    __syncthreads();

    // act[row][col] f16, col = h*32 + td*16 + g*4 (+0..3); byte-level swizzle:
    // addr = row*1024 + ((chunk ^ (row&7))<<4) + (col&7)*2, chunk = col>>3
#pragma unroll
    for (int ti = 0; ti < 4; ++ti) {
        int tok = ti * 16 + c16;
        if (tok < NTOK) {
#pragma unroll
            for (int td = 0; td < 2; ++td) {
                f32x4 v = O2[td][ti];
                float iv = inv[ti];
                f16x4 o = { (f16)(v[0] * iv), (f16)(v[1] * iv),
                            (f16)(v[2] * iv), (f16)(v[3] * iv) };
                int col = h * 32 + td * 16 + g * 4;
                int chunk = (col >> 3) ^ (tok & 7);
                *(f16x4*)((char*)act + tok * 1024 + (chunk << 4) + (col & 7) * 2) = o;
            }
        }
    }
    // zero pad rows 49..63 of this wave's col-slice (4 chunks/row x 15 rows = 60 writes)
    if (l < 60) {
        int row = 49 + (l >> 2);
        int chunk = (h * 4 + (l & 3)) ^ (row & 7);
        *(f16x8*)((char*)act + row * 1024 + (chunk << 4)) = z8;
    }
    __syncthreads();

    // ---- phase 3: proj. wave h: n-slice [h*32, h*32+32), m rows 0..63 (store m<49) ----
    f32x4 pacc[2][4];
#pragma unroll
    for (int j = 0; j < 2; ++j)
#pragma unroll
        for (int i = 0; i < 4; ++i) pacc[j][i] = zf;

    // W rows n = h*32 + j*16 + c16, k = ks*32 + g*8
    const f16* gW0 = pw16 + (size_t)(h * 32 + c16) * DIM + g * 8;
    f16x8 bfc[2];
#pragma unroll
    for (int j = 0; j < 2; ++j)
        bfc[j] = *(const f16x8*)(gW0 + (size_t)(j * 16) * DIM);

#pragma unroll
    for (int ks = 0; ks < 16; ++ks) {
        f16x8 af[4];
#pragma unroll
        for (int i = 0; i < 4; ++i) {
            int m = i * 16 + c16;
            int chunk = (ks * 4 + g) ^ (m & 7);
            af[i] = *(const f16x8*)((char*)act + m * 1024 + (chunk << 4));
        }
        f16x8 bfn[2];
        if (ks + 1 < 16) {
#pragma unroll
            for (int j = 0; j < 2; ++j)
                bfn[j] = *(const f16x8*)(gW0 + (size_t)(j * 16) * DIM + (ks + 1) * 32);
        }
        __builtin_amdgcn_s_setprio(1);
#pragma unroll
        for (int j = 0; j < 2; ++j)
#pragma unroll
            for (int i = 0; i < 4; ++i)
                pacc[j][i] = __builtin_amdgcn_mfma_f32_16x16x32_f16(bfc[j], af[i], pacc[j][i], 0, 0, 0);
        __builtin_amdgcn_s_setprio(0);
        bfc[0] = bfn[0]; bfc[1] = bfn[1];
    }

    // epilogue: C^T lane col m = i*16+c16; rows n = h*32 + j*16 + g*4 (+0..3)
#pragma unroll
    for (int i = 0; i < 4; ++i) {
        const int m = i * 16 + c16;
        if (m < NTOK) {
#pragma unroll
            for (int j = 0; j < 2; ++j) {
                const int n = h * 32 + j * 16 + g * 4;
                f32x4 v = pacc[j][i];
                v += *(const f32x4*)&projb[n];
                float4 o = { v[0], v[1], v[2], v[3] };
                *(float4*)(outp + ((size_t)(b * NTOK + m)) * DIM + n) = o;
            }
        }
    }
}

// ---------------- launcher ----------------
extern "C" void kernel_launch(void* const* d_in, const int* in_sizes, int n_in,
                              void* d_out, int out_size, void* d_ws, size_t ws_size,
                              hipStream_t stream) {
    const float* x      = (const float*)d_in[0];
    const float* mask   = (const float*)d_in[1];
    const float* rpb    = (const float*)d_in[2];
    const float* qkv_w  = (const float*)d_in[3];
    const float* qkv_b  = (const float*)d_in[4];
    const float* proj_w = (const float*)d_in[5];
    const float* proj_b = (const float*)d_in[6];
    float* out = (float*)d_out;

    char* ws = (char*)d_ws;
    size_t o = 0;
    f16* x16   = (f16*)(ws + o); o += (size_t)MTOT * DIM * 2;
    f16* w16   = (f16*)(ws + o); o += (size_t)1536 * 512 * 2;
    f16* pw16  = (f16*)(ws + o); o += (size_t)512 * 512 * 2;
    f16* qws   = (f16*)(ws + o); o += (size_t)NB * NH * NTOK * HD * 2;
    f16* kws   = (f16*)(ws + o); o += (size_t)NB * NH * NTOK * HD * 2;
    f16* vtws  = (f16*)(ws + o); o += (size_t)NB * NH * HD * VTS * 2;
    f16* bT    = (f16*)(ws + o); o += (size_t)NH * 64 * 64 * 2;       // 131 KB
    f16* mT    = (f16*)(ws + o); o += (size_t)NWIN * 64 * 64 * 2;     // 524 KB

    // tables + all converts in one launch
    prep_kernel<<<dim3(1280 + 2048 + 768 + 256), dim3(256), 0, stream>>>(
        rpb, mask, bT, mT, qkv_w, w16, proj_w, pw16, x, x16);

    // QKV: 392 m-tiles x 6 n-tiles = 2352 blocks (divisible by 8)
    gemm256<6><<<dim3((MTOT / 256) * 6), dim3(512), 0, stream>>>(
        x16, w16, qkv_b, qws, kws, vtws);

    // fused attention + projection: 1 block per window, 16 waves = 16 heads
    attn_proj_kernel<<<dim3(NB), dim3(1024), 0, stream>>>(
        qws, kws, vtws, bT, mT, pw16, proj_b, out);
}

// Round 17
// 529.493 us; speedup vs baseline: 1.0439x; 1.0439x over previous
//
#include <hip/hip_runtime.h>

typedef _Float16 f16;
typedef _Float16 f16x8 __attribute__((ext_vector_type(8)));
typedef _Float16 f16x4 __attribute__((ext_vector_type(4)));
typedef __fp16 fp16x2 __attribute__((ext_vector_type(2)));
typedef float f32x4 __attribute__((ext_vector_type(4)));

#define NTOK 49
#define NH 16
#define HD 32
#define DIM 512
#define NWIN 64
#define NB 2048
#define MTOT (NB*NTOK)      // 100352
#define SCALE 0.17677669529663687f
#define VTS 56              // vt t-stride (padded, 16B-aligned rows)

__device__ __forceinline__ void gload_lds16(const f16* g, f16* l) {
    __builtin_amdgcn_global_load_lds((const __attribute__((address_space(1))) void*)g,
                                     (__attribute__((address_space(3))) void*)l, 16, 0, 0);
}

// ---------------- convert fp32 -> fp16 (vectorized) ----------------
__device__ __forceinline__ void cvt_body(const float* __restrict__ s, f16* __restrict__ d,
                                         int n4, int bid, int nb) {
    int i = bid * 256 + threadIdx.x;
    int st = nb * 256;
    for (; i < n4; i += st) {
        float4 v = ((const float4*)s)[i];
        f16x4 o = { (f16)v.x, (f16)v.y, (f16)v.z, (f16)v.w };
        *(f16x4*)(d + (size_t)i * 4) = o;
    }
}

// ---- prep kernel: comb2T build + x/qkv_w/proj_w converts, one launch ----
// comb2T: TRANSPOSED bias+mask in MFMA-fragment layout for S^T attention:
//   element at (k = ti*16+g*4+r4, q = tj*16+c16):
//   k>=49 -> -30000 (softmax kill), q>=49 -> 0, else bias[q][k]+mask[w][q][k]
__global__ __launch_bounds__(256) void prep_kernel(const float* __restrict__ rpb,
                                                   const float* __restrict__ mask,
                                                   f16* __restrict__ comb2,
                                                   const float* __restrict__ qkvw,
                                                   f16* __restrict__ w16,
                                                   const float* __restrict__ projw,
                                                   f16* __restrict__ pw16,
                                                   const float* __restrict__ x,
                                                   f16* __restrict__ x16) {
    const int bid = blockIdx.x;
    if (bid >= 16384) {
        if (bid < 16384 + 2048)      cvt_body(x, x16, MTOT * DIM / 4, bid - 16384, 2048);
        else if (bid < 16384 + 2816) cvt_body(qkvw, w16, 1536 * 512 / 4, bid - 16384 - 2048, 768);
        else                         cvt_body(projw, pw16, 512 * 512 / 4, bid - 16384 - 2816, 256);
        return;
    }
    int idx = bid * 256 + threadIdx.x;   // total = 1024 * 64 * 64
    int r4   = idx & 3;
    int tj   = (idx >> 2) & 3;
    int ti   = (idx >> 4) & 3;
    int lane = (idx >> 6) & 63;
    int wh   = idx >> 12;           // w*16 + h
    int h = wh & 15, w = wh >> 4;
    int g = lane >> 4, c16 = lane & 15;
    int k = ti * 16 + g * 4 + r4;   // k token
    int q = tj * 16 + c16;          // q token
    float v;
    if (k >= NTOK)      v = -30000.f;
    else if (q >= NTOK) v = 0.f;
    else {
        int rq = q / 7, cq = q - rq * 7;
        int rk = k / 7, ck = k - rk * 7;
        int rel = (rq - rk + 6) * 13 + (cq - ck + 6);
        v = rpb[rel * NH + h] + mask[(w * NTOK + q) * NTOK + k];
    }
    comb2[idx] = (f16)v;
}

#define WAIT_LGKM  asm volatile("s_waitcnt lgkmcnt(0)" ::: "memory")
#define WAIT_VM(N) asm volatile("s_waitcnt vmcnt(" #N ")" ::: "memory")

// ---------------- 256x256 GEMM (QKV), register-double-buffered k-half pipeline ----------------
// (r9/r12 kernel — best of 7 schedule/tile attempts at ~230 us)
template<int NT>   // NT = N/256 tiles
__global__ __launch_bounds__(512) void gemm256(const f16* __restrict__ A,
                                               const f16* __restrict__ Bw,
                                               const float* __restrict__ bias,
                                               f16* __restrict__ qo,
                                               f16* __restrict__ ko,
                                               f16* __restrict__ vto) {
    __shared__ __align__(16) f16 As[2][256][64];
    __shared__ __align__(16) f16 Bs[2][256][64];

    const int tid = threadIdx.x;
    const int lane = tid & 63;
    const int wv = tid >> 6;                 // 0..7
    const int wm = wv >> 2, wn = wv & 3;     // 2M x 4N wave grid
    const int g = lane >> 4, c16 = lane & 15;

    const int nblk = gridDim.x;
    const int f = blockIdx.x;
    const int work = (f & 7) * (nblk >> 3) + (f >> 3);
    const int m0 = (work / NT) * 256;
    const int n0 = (work % NT) * 256;

    const int srow = lane >> 3;
    const int schunk = (lane & 7) ^ srow;
    const f16* gA = A  + (size_t)(m0 + wv * 16 + srow) * DIM + schunk * 8;
    const f16* gB = Bw + (size_t)(n0 + wv * 16 + srow) * DIM + schunk * 8;

#define STAGE1(buf, kt, role) do {                                             \
    const f16* _s = (((role) < 2) ? gA : gB) + (size_t)(((role) & 1) * 128) * DIM + (kt) * 64; \
    f16* _d = ((role) < 2) ? &As[buf][((role) & 1) * 128 + wv * 16][0]         \
                           : &Bs[buf][((role) & 1) * 128 + wv * 16][0];        \
    gload_lds16(_s, _d);                                                       \
    gload_lds16(_s + (size_t)8 * DIM, _d + 8 * 64);                            \
} while (0)
#define STAGE_T(buf, kt) do { STAGE1(buf, kt, 0); STAGE1(buf, kt, 1);          \
                              STAGE1(buf, kt, 2); STAGE1(buf, kt, 3); } while (0)

#define READS(buf, kk, AF, BF) do {                                            \
    _Pragma("unroll") for (int _i = 0; _i < 8; ++_i)                           \
        (AF)[_i] = *(const f16x8*)&As[buf][wm * 128 + _i * 16 + c16][(((kk) * 4 + g) ^ (c16 & 7)) * 8]; \
    _Pragma("unroll") for (int _j = 0; _j < 4; ++_j)                           \
        (BF)[_j] = *(const f16x8*)&Bs[buf][wn * 64 + _j * 16 + c16][(((kk) * 4 + g) ^ (c16 & 7)) * 8]; \
} while (0)

#define MM(AF, BF) do {                                                        \
    __builtin_amdgcn_s_setprio(1);                                             \
    _Pragma("unroll") for (int _j = 0; _j < 4; ++_j)                           \
    _Pragma("unroll") for (int _i = 0; _i < 8; ++_i)                           \
        acc[_j][_i] = __builtin_amdgcn_mfma_f32_16x16x32_f16((BF)[_j], (AF)[_i], acc[_j][_i], 0, 0, 0); \
    __builtin_amdgcn_s_setprio(0);                                             \
} while (0)

    f32x4 acc[4][8];
#pragma unroll
    for (int j = 0; j < 4; ++j)
#pragma unroll
        for (int i = 0; i < 8; ++i)
            acc[j][i] = (f32x4){0.f, 0.f, 0.f, 0.f};

    f16x8 a0[8], b0[4], a1[8], b1[4];

    const int KT = DIM / 64;   // 8 K-tiles

    STAGE_T(0, 0);
    STAGE_T(1, 1);
    WAIT_VM(8);
    __builtin_amdgcn_s_barrier();
    READS(0, 0, a0, b0);

#pragma unroll
    for (int t = 0; t < KT; ++t) {
        const int b = t & 1, nb = b ^ 1;

        READS(b, 1, a1, b1);
        MM(a0, b0);
        WAIT_LGKM;
        __builtin_amdgcn_s_barrier();
        if (t + 2 < KT) STAGE_T(b, t + 2);
        if (t + 2 < KT) { WAIT_VM(8); }
        else if (t + 1 < KT) { WAIT_VM(0); }

        if (t + 1 < KT) READS(nb, 0, a0, b0);
        MM(a1, b1);
    }
#undef STAGE1
#undef STAGE_T
#undef READS
#undef MM

#pragma unroll
    for (int i = 0; i < 8; ++i) {
        const int m = m0 + wm * 128 + i * 16 + c16;
        const int bb = m / NTOK, tk = m - (m / NTOK) * NTOK;
#pragma unroll
        for (int j = 0; j < 4; ++j) {
            const int n = n0 + wn * 64 + j * 16 + g * 4;
            f32x4 v = acc[j][i];
            const f32x4 b4 = *(const f32x4*)&bias[n];
            v += b4;
            const int s = n >> 9;
            const int hh = (n >> 5) & 15;
            const int d0 = n & 31;
            const size_t bh = (size_t)(bb * NH + hh);
            if (s == 0) {
                f16x4 o = { (f16)(v[0] * SCALE), (f16)(v[1] * SCALE),
                            (f16)(v[2] * SCALE), (f16)(v[3] * SCALE) };
                *(f16x4*)(qo + (bh * NTOK + tk) * HD + d0) = o;
            } else if (s == 1) {
                f16x4 o = { (f16)v[0], (f16)v[1], (f16)v[2], (f16)v[3] };
                *(f16x4*)(ko + (bh * NTOK + tk) * HD + d0) = o;
            } else {
#pragma unroll
                for (int r = 0; r < 4; ++r)
                    vto[(bh * HD + d0 + r) * VTS + tk] = (f16)v[r];
            }
        }
    }
}

// ---------------- 128x128 GEMM (proj): BK=32, triple-buffered, 3 blocks/CU ----------------
__global__ __launch_bounds__(256, 3) void gemm128(const f16* __restrict__ A,
                                                  const f16* __restrict__ Bw,
                                                  const float* __restrict__ bias,
                                                  float* __restrict__ outp) {
    __shared__ __align__(16) f16 As[3][128][32];
    __shared__ __align__(16) f16 Bs[3][128][32];

    const int NT = 4;   // 512/128
    const int tid = threadIdx.x;
    const int lane = tid & 63;
    const int wv = tid >> 6;
    const int wr = wv >> 1, wc = wv & 1;
    const int g = lane >> 4, c16 = lane & 15;
    const int rsw = (c16 >> 1) & 3;

    const int nblk = gridDim.x;
    const int f = blockIdx.x;
    const int work = (f & 7) * (nblk >> 3) + (f >> 3);
    const int m0 = (work / NT) * 128;
    const int n0 = (work % NT) * 128;

    const int srow = lane >> 2;
    const int schunk = (lane & 3) ^ ((srow >> 1) & 3);
    const f16* gA = A  + (size_t)(m0 + wv * 32 + srow) * DIM + schunk * 8;
    const f16* gB = Bw + (size_t)(n0 + wv * 32 + srow) * DIM + schunk * 8;

#define STAGE6(buf, t) do { \
    gload_lds16(gA + (t) * 32,                     &As[buf][wv * 32][0]);      \
    gload_lds16(gA + (size_t)16 * DIM + (t) * 32,  &As[buf][wv * 32 + 16][0]); \
    gload_lds16(gB + (t) * 32,                     &Bs[buf][wv * 32][0]);      \
    gload_lds16(gB + (size_t)16 * DIM + (t) * 32,  &Bs[buf][wv * 32 + 16][0]); \
} while (0)

    f32x4 acc[4][4];   // acc[j][i] = C^T
#pragma unroll
    for (int j = 0; j < 4; ++j)
#pragma unroll
        for (int i = 0; i < 4; ++i)
            acc[j][i] = (f32x4){0.f, 0.f, 0.f, 0.f};

    STAGE6(0, 0);
    STAGE6(1, 1);
    WAIT_VM(4);
    __builtin_amdgcn_s_barrier();

    const int KS = DIM / 32;   // 16 K-steps
#pragma unroll
    for (int t = 0; t < KS; ++t) {
        const int cb = t % 3;
        if (t + 2 < KS) STAGE6((t + 2) % 3, t + 2);
        f16x8 af[4], bf[4];
#pragma unroll
        for (int i = 0; i < 4; ++i)
            af[i] = *(const f16x8*)&As[cb][wr * 64 + i * 16 + c16][(g ^ rsw) * 8];
#pragma unroll
        for (int j = 0; j < 4; ++j)
            bf[j] = *(const f16x8*)&Bs[cb][wc * 64 + j * 16 + c16][(g ^ rsw) * 8];
        __builtin_amdgcn_s_setprio(1);
#pragma unroll
        for (int j = 0; j < 4; ++j)
#pragma unroll
            for (int i = 0; i < 4; ++i)
                acc[j][i] = __builtin_amdgcn_mfma_f32_16x16x32_f16(bf[j], af[i], acc[j][i], 0, 0, 0);
        __builtin_amdgcn_s_setprio(0);
        WAIT_LGKM;
        __builtin_amdgcn_sched_barrier(0);
        if (t + 2 < KS) {
            WAIT_VM(4);
        } else if (t + 1 < KS) {
            WAIT_VM(0);
        }
        if (t + 1 < KS) __builtin_amdgcn_s_barrier();
    }
#undef STAGE6

#pragma unroll
    for (int i = 0; i < 4; ++i) {
        const int m = m0 + wr * 64 + i * 16 + c16;
#pragma unroll
        for (int j = 0; j < 4; ++j) {
            const int n = n0 + wc * 64 + j * 16 + g * 4;
            f32x4 v = acc[j][i];
            const f32x4 b4 = *(const f32x4*)&bias[n];
            v += b4;
            float4 o = { v[0], v[1], v[2], v[3] };
            *(float4*)(outp + (size_t)m * DIM + n) = o;
        }
    }
}

// ---------------- fused window attention v2: S^T + in-lane softmax ----------------
// 4 waves/block, 1 wave per (b,h), waves fully independent (no __syncthreads).
// S^T[k][q] = mfma(kf, qf, comb2T): lane holds q=c16 (per q-tile j), k=16i+4g+r.
// Row-softmax = in-lane 16-max/sum + 2 shfl_xor (16,32). k>=49 killed via -30000
// in table. Normalization deferred to O epilogue (inv[j] per lane matches q=c16).
// P packed to fp16x2 (cvt_pkrtz) -> 32 ds_write_b32 into wave-private Ps slice;
// lgkmcnt(0) (not syncthreads) orders write->read.
__global__ __launch_bounds__(256) void attn_kernel(const f16* __restrict__ qw,
                                                   const f16* __restrict__ kw,
                                                   const f16* __restrict__ vt,
                                                   const f16* __restrict__ comb2,
                                                   f16* __restrict__ aout) {
    __shared__ __align__(16) f16 Ps[4][64][72];

    const int wv = threadIdx.x >> 6;
    const int l = threadIdx.x & 63;
    const int f = blockIdx.x;
    const int work = (f & 7) * (gridDim.x >> 3) + (f >> 3);
    const int bid = work * 4 + wv;
    const int b = bid >> 4, h = bid & 15;
    const int w = b & (NWIN - 1);
    const int g = l >> 4, c16 = l & 15;
    const size_t qkbase = (size_t)bid * (NTOK * HD);
    const size_t vbase = (size_t)bid * (HD * VTS);

    const f16x8 z8 = {};

    f16x8 qf[4], kf[4];
#pragma unroll
    for (int t = 0; t < 4; ++t) {
        int row = t * 16 + c16;
        f16x8 q = z8, k = z8;
        if (row < NTOK) {
            q = *(const f16x8*)(qw + qkbase + row * HD + g * 8);
            k = *(const f16x8*)(kw + qkbase + row * HD + g * 8);
        }
        qf[t] = q; kf[t] = k;
    }

    const f16* cb = comb2 + (((size_t)(w * NH + h) * 64 + l) << 6);
    f16x8 cbv[8];
#pragma unroll
    for (int k = 0; k < 8; ++k) cbv[k] = *(const f16x8*)(cb + k * 8);
    f32x4 St[4][4];   // St[i][j]: i = k-tile, j = q-tile
#pragma unroll
    for (int i = 0; i < 4; ++i)
#pragma unroll
        for (int j = 0; j < 4; ++j) {
            const int e = i * 16 + j * 4;
#pragma unroll
            for (int r = 0; r < 4; ++r)
                St[i][j][r] = (float)cbv[(e + r) >> 3][(e + r) & 7];
        }
#pragma unroll
    for (int i = 0; i < 4; ++i)
#pragma unroll
        for (int j = 0; j < 4; ++j)
            St[i][j] = __builtin_amdgcn_mfma_f32_16x16x32_f16(kf[i], qf[j], St[i][j], 0, 0, 0);

    float inv[4];
#pragma unroll
    for (int j = 0; j < 4; ++j) {
        float m = St[0][j][0];
#pragma unroll
        for (int i = 0; i < 4; ++i)
#pragma unroll
            for (int r = 0; r < 4; ++r) m = fmaxf(m, St[i][j][r]);
        m = fmaxf(m, __shfl_xor(m, 16, 64));
        m = fmaxf(m, __shfl_xor(m, 32, 64));
        float s = 0.f;
#pragma unroll
        for (int i = 0; i < 4; ++i)
#pragma unroll
            for (int r = 0; r < 4; ++r) {
                float p = __expf(St[i][j][r] - m);
                St[i][j][r] = p;
                s += p;
            }
        s += __shfl_xor(s, 16, 64);
        s += __shfl_xor(s, 32, 64);
        inv[j] = 1.f / s;
    }

#pragma unroll
    for (int j = 0; j < 4; ++j) {
        const int q = j * 16 + c16;
#pragma unroll
        for (int i = 0; i < 4; ++i) {
            fp16x2 u0 = __builtin_amdgcn_cvt_pkrtz(St[i][j][0], St[i][j][1]);
            fp16x2 u1 = __builtin_amdgcn_cvt_pkrtz(St[i][j][2], St[i][j][3]);
            *(fp16x2*)&Ps[wv][q][i * 16 + 4 * g]     = u0;
            *(fp16x2*)&Ps[wv][q][i * 16 + 4 * g + 2] = u1;
        }
    }
    WAIT_LGKM;   // wave-private region: write->read ordering only

    f32x4 O2[2][4];
    const f32x4 zf = (f32x4){0.f, 0.f, 0.f, 0.f};
#pragma unroll
    for (int td = 0; td < 2; ++td)
#pragma unroll
        for (int ti = 0; ti < 4; ++ti) O2[td][ti] = zf;
#pragma unroll
    for (int c = 0; c < 2; ++c) {
        f16x8 pf[4], vf[2];
#pragma unroll
        for (int ti = 0; ti < 4; ++ti)
            pf[ti] = *(const f16x8*)&Ps[wv][ti * 16 + c16][c * 32 + g * 8];
        int tcol = c * 32 + g * 8;
#pragma unroll
        for (int td = 0; td < 2; ++td) {
            f16x8 vv = z8;
            if (tcol < VTS)
                vv = *(const f16x8*)(vt + vbase + (size_t)(td * 16 + c16) * VTS + tcol);
            vf[td] = vv;
        }
#pragma unroll
        for (int td = 0; td < 2; ++td)
#pragma unroll
            for (int ti = 0; ti < 4; ++ti)
                O2[td][ti] = __builtin_amdgcn_mfma_f32_16x16x32_f16(vf[td], pf[ti], O2[td][ti], 0, 0, 0);
    }

#pragma unroll
    for (int ti = 0; ti < 4; ++ti) {
        int tok = ti * 16 + c16;
        if (tok < NTOK) {
            size_t ob = ((size_t)(b * NTOK + tok)) * DIM + h * HD;
#pragma unroll
            for (int td = 0; td < 2; ++td) {
                f32x4 v = O2[td][ti];
                float iv = inv[ti];
                f16x4 o = { (f16)(v[0] * iv), (f16)(v[1] * iv),
                            (f16)(v[2] * iv), (f16)(v[3] * iv) };
                *(f16x4*)(aout + ob + td * 16 + g * 4) = o;
            }
        }
    }
}

// ---------------- launcher ----------------
extern "C" void kernel_launch(void* const* d_in, const int* in_sizes, int n_in,
                              void* d_out, int out_size, void* d_ws, size_t ws_size,
                              hipStream_t stream) {
    const float* x      = (const float*)d_in[0];
    const float* mask   = (const float*)d_in[1];
    const float* rpb    = (const float*)d_in[2];
    const float* qkv_w  = (const float*)d_in[3];
    const float* qkv_b  = (const float*)d_in[4];
    const float* proj_w = (const float*)d_in[5];
    const float* proj_b = (const float*)d_in[6];
    float* out = (float*)d_out;

    char* ws = (char*)d_ws;
    size_t o = 0;
    f16* x16   = (f16*)(ws + o); o += (size_t)MTOT * DIM * 2;
    f16* w16   = (f16*)(ws + o); o += (size_t)1536 * 512 * 2;
    f16* pw16  = (f16*)(ws + o); o += (size_t)512 * 512 * 2;
    f16* qws   = (f16*)(ws + o); o += (size_t)NB * NH * NTOK * HD * 2;
    f16* kws   = (f16*)(ws + o); o += (size_t)NB * NH * NTOK * HD * 2;
    f16* vtws  = (f16*)(ws + o); o += (size_t)NB * NH * HD * VTS * 2;
    f16* cb2   = (f16*)(ws + o);
    f16* aout = x16;   // x16 dead after QKV GEMM

    // all converts + comb2T in one launch
    prep_kernel<<<dim3(16384 + 2048 + 768 + 256), dim3(256), 0, stream>>>(
        rpb, mask, cb2, qkv_w, w16, proj_w, pw16, x, x16);

    // QKV: 392 m-tiles x 6 n-tiles = 2352 blocks (divisible by 8)
    gemm256<6><<<dim3((MTOT / 256) * 6), dim3(512), 0, stream>>>(
        x16, w16, qkv_b, qws, kws, vtws);

    attn_kernel<<<dim3(NB * NH / 4), dim3(256), 0, stream>>>(qws, kws, vtws, cb2, aout);

    // proj: 784 x 4 = 3136 blocks, 128^2 tile, 3 blocks/CU
    gemm128<<<dim3((MTOT / 128) * 4), dim3(256), 0, stream>>>(
        aout, pw16, proj_b, out);
}

// Round 18
// 527.233 us; speedup vs baseline: 1.0483x; 1.0043x over previous
//
#include <hip/hip_runtime.h>

typedef _Float16 f16;
typedef _Float16 f16x8 __attribute__((ext_vector_type(8)));
typedef _Float16 f16x4 __attribute__((ext_vector_type(4)));
typedef __fp16 fp16x2 __attribute__((ext_vector_type(2)));
typedef float f32x4 __attribute__((ext_vector_type(4)));

#define NTOK 49
#define NH 16
#define HD 32
#define DIM 512
#define NWIN 64
#define NB 2048
#define MTOT (NB*NTOK)      // 100352
#define SCALE 0.17677669529663687f
#define VTS 56              // vt t-stride (padded, 16B-aligned rows)

__device__ __forceinline__ void gload_lds16(const f16* g, f16* l) {
    __builtin_amdgcn_global_load_lds((const __attribute__((address_space(1))) void*)g,
                                     (__attribute__((address_space(3))) void*)l, 16, 0, 0);
}

// ---------------- convert fp32 -> fp16 (vectorized) ----------------
__device__ __forceinline__ void cvt_body(const float* __restrict__ s, f16* __restrict__ d,
                                         int n4, int bid, int nb) {
    int i = bid * 256 + threadIdx.x;
    int st = nb * 256;
    for (; i < n4; i += st) {
        float4 v = ((const float4*)s)[i];
        f16x4 o = { (f16)v.x, (f16)v.y, (f16)v.z, (f16)v.w };
        *(f16x4*)(d + (size_t)i * 4) = o;
    }
}

// ---- prep kernel: comb2T build + x/qkv_w/proj_w converts, one launch ----
__global__ __launch_bounds__(256) void prep_kernel(const float* __restrict__ rpb,
                                                   const float* __restrict__ mask,
                                                   f16* __restrict__ comb2,
                                                   const float* __restrict__ qkvw,
                                                   f16* __restrict__ w16,
                                                   const float* __restrict__ projw,
                                                   f16* __restrict__ pw16,
                                                   const float* __restrict__ x,
                                                   f16* __restrict__ x16) {
    const int bid = blockIdx.x;
    if (bid >= 16384) {
        if (bid < 16384 + 2048)      cvt_body(x, x16, MTOT * DIM / 4, bid - 16384, 2048);
        else if (bid < 16384 + 2816) cvt_body(qkvw, w16, 1536 * 512 / 4, bid - 16384 - 2048, 768);
        else                         cvt_body(projw, pw16, 512 * 512 / 4, bid - 16384 - 2816, 256);
        return;
    }
    int idx = bid * 256 + threadIdx.x;   // total = 1024 * 64 * 64
    int r4   = idx & 3;
    int tj   = (idx >> 2) & 3;
    int ti   = (idx >> 4) & 3;
    int lane = (idx >> 6) & 63;
    int wh   = idx >> 12;           // w*16 + h
    int h = wh & 15, w = wh >> 4;
    int g = lane >> 4, c16 = lane & 15;
    int k = ti * 16 + g * 4 + r4;   // k token
    int q = tj * 16 + c16;          // q token
    float v;
    if (k >= NTOK)      v = -30000.f;
    else if (q >= NTOK) v = 0.f;
    else {
        int rq = q / 7, cq = q - rq * 7;
        int rk = k / 7, ck = k - rk * 7;
        int rel = (rq - rk + 6) * 13 + (cq - ck + 6);
        v = rpb[rel * NH + h] + mask[(w * NTOK + q) * NTOK + k];
    }
    comb2[idx] = (f16)v;
}

#define WAIT_LGKM  asm volatile("s_waitcnt lgkmcnt(0)" ::: "memory")
#define WAIT_VM(N) asm volatile("s_waitcnt vmcnt(" #N ")" ::: "memory")

// ---------------- 256x256 GEMM (QKV), register-double-buffered k-half pipeline ----------------
template<int NT>   // NT = N/256 tiles
__global__ __launch_bounds__(512) void gemm256(const f16* __restrict__ A,
                                               const f16* __restrict__ Bw,
                                               const float* __restrict__ bias,
                                               f16* __restrict__ qo,
                                               f16* __restrict__ ko,
                                               f16* __restrict__ vto) {
    __shared__ __align__(16) f16 As[2][256][64];
    __shared__ __align__(16) f16 Bs[2][256][64];

    const int tid = threadIdx.x;
    const int lane = tid & 63;
    const int wv = tid >> 6;                 // 0..7
    const int wm = wv >> 2, wn = wv & 3;     // 2M x 4N wave grid
    const int g = lane >> 4, c16 = lane & 15;

    const int nblk = gridDim.x;
    const int f = blockIdx.x;
    const int work = (f & 7) * (nblk >> 3) + (f >> 3);
    const int m0 = (work / NT) * 256;
    const int n0 = (work % NT) * 256;

    const int srow = lane >> 3;
    const int schunk = (lane & 7) ^ srow;
    const f16* gA = A  + (size_t)(m0 + wv * 16 + srow) * DIM + schunk * 8;
    const f16* gB = Bw + (size_t)(n0 + wv * 16 + srow) * DIM + schunk * 8;

#define STAGE1(buf, kt, role) do {                                             \
    const f16* _s = (((role) < 2) ? gA : gB) + (size_t)(((role) & 1) * 128) * DIM + (kt) * 64; \
    f16* _d = ((role) < 2) ? &As[buf][((role) & 1) * 128 + wv * 16][0]         \
                           : &Bs[buf][((role) & 1) * 128 + wv * 16][0];        \
    gload_lds16(_s, _d);                                                       \
    gload_lds16(_s + (size_t)8 * DIM, _d + 8 * 64);                            \
} while (0)
#define STAGE_T(buf, kt) do { STAGE1(buf, kt, 0); STAGE1(buf, kt, 1);          \
                              STAGE1(buf, kt, 2); STAGE1(buf, kt, 3); } while (0)

#define READS(buf, kk, AF, BF) do {                                            \
    _Pragma("unroll") for (int _i = 0; _i < 8; ++_i)                           \
        (AF)[_i] = *(const f16x8*)&As[buf][wm * 128 + _i * 16 + c16][(((kk) * 4 + g) ^ (c16 & 7)) * 8]; \
    _Pragma("unroll") for (int _j = 0; _j < 4; ++_j)                           \
        (BF)[_j] = *(const f16x8*)&Bs[buf][wn * 64 + _j * 16 + c16][(((kk) * 4 + g) ^ (c16 & 7)) * 8]; \
} while (0)

#define MM(AF, BF) do {                                                        \
    __builtin_amdgcn_s_setprio(1);                                             \
    _Pragma("unroll") for (int _j = 0; _j < 4; ++_j)                           \
    _Pragma("unroll") for (int _i = 0; _i < 8; ++_i)                           \
        acc[_j][_i] = __builtin_amdgcn_mfma_f32_16x16x32_f16((BF)[_j], (AF)[_i], acc[_j][_i], 0, 0, 0); \
    __builtin_amdgcn_s_setprio(0);                                             \
} while (0)

    f32x4 acc[4][8];
#pragma unroll
    for (int j = 0; j < 4; ++j)
#pragma unroll
        for (int i = 0; i < 8; ++i)
            acc[j][i] = (f32x4){0.f, 0.f, 0.f, 0.f};

    f16x8 a0[8], b0[4], a1[8], b1[4];

    const int KT = DIM / 64;   // 8 K-tiles

    STAGE_T(0, 0);
    STAGE_T(1, 1);
    WAIT_VM(8);
    __builtin_amdgcn_s_barrier();
    READS(0, 0, a0, b0);

#pragma unroll
    for (int t = 0; t < KT; ++t) {
        const int b = t & 1, nb = b ^ 1;

        READS(b, 1, a1, b1);
        MM(a0, b0);
        WAIT_LGKM;
        __builtin_amdgcn_s_barrier();
        if (t + 2 < KT) STAGE_T(b, t + 2);
        if (t + 2 < KT) { WAIT_VM(8); }
        else if (t + 1 < KT) { WAIT_VM(0); }

        if (t + 1 < KT) READS(nb, 0, a0, b0);
        MM(a1, b1);
    }
#undef STAGE1
#undef STAGE_T
#undef READS
#undef MM

#pragma unroll
    for (int i = 0; i < 8; ++i) {
        const int m = m0 + wm * 128 + i * 16 + c16;
        const int bb = m / NTOK, tk = m - (m / NTOK) * NTOK;
#pragma unroll
        for (int j = 0; j < 4; ++j) {
            const int n = n0 + wn * 64 + j * 16 + g * 4;
            f32x4 v = acc[j][i];
            const f32x4 b4 = *(const f32x4*)&bias[n];
            v += b4;
            const int s = n >> 9;
            const int hh = (n >> 5) & 15;
            const int d0 = n & 31;
            const size_t bh = (size_t)(bb * NH + hh);
            if (s == 0) {
                f16x4 o = { (f16)(v[0] * SCALE), (f16)(v[1] * SCALE),
                            (f16)(v[2] * SCALE), (f16)(v[3] * SCALE) };
                *(f16x4*)(qo + (bh * NTOK + tk) * HD + d0) = o;
            } else if (s == 1) {
                f16x4 o = { (f16)v[0], (f16)v[1], (f16)v[2], (f16)v[3] };
                *(f16x4*)(ko + (bh * NTOK + tk) * HD + d0) = o;
            } else {
#pragma unroll
                for (int r = 0; r < 4; ++r)
                    vto[(bh * HD + d0 + r) * VTS + tk] = (f16)v[r];
            }
        }
    }
}

// ---------------- 128x128 GEMM (proj): BK=32, triple-buffered, 3 blocks/CU ----------------
__global__ __launch_bounds__(256, 3) void gemm128(const f16* __restrict__ A,
                                                  const f16* __restrict__ Bw,
                                                  const float* __restrict__ bias,
                                                  float* __restrict__ outp) {
    __shared__ __align__(16) f16 As[3][128][32];
    __shared__ __align__(16) f16 Bs[3][128][32];

    const int NT = 4;   // 512/128
    const int tid = threadIdx.x;
    const int lane = tid & 63;
    const int wv = tid >> 6;
    const int wr = wv >> 1, wc = wv & 1;
    const int g = lane >> 4, c16 = lane & 15;
    const int rsw = (c16 >> 1) & 3;

    const int nblk = gridDim.x;
    const int f = blockIdx.x;
    const int work = (f & 7) * (nblk >> 3) + (f >> 3);
    const int m0 = (work / NT) * 128;
    const int n0 = (work % NT) * 128;

    const int srow = lane >> 2;
    const int schunk = (lane & 3) ^ ((srow >> 1) & 3);
    const f16* gA = A  + (size_t)(m0 + wv * 32 + srow) * DIM + schunk * 8;
    const f16* gB = Bw + (size_t)(n0 + wv * 32 + srow) * DIM + schunk * 8;

#define STAGE6(buf, t) do { \
    gload_lds16(gA + (t) * 32,                     &As[buf][wv * 32][0]);      \
    gload_lds16(gA + (size_t)16 * DIM + (t) * 32,  &As[buf][wv * 32 + 16][0]); \
    gload_lds16(gB + (t) * 32,                     &Bs[buf][wv * 32][0]);      \
    gload_lds16(gB + (size_t)16 * DIM + (t) * 32,  &Bs[buf][wv * 32 + 16][0]); \
} while (0)

    f32x4 acc[4][4];   // acc[j][i] = C^T
#pragma unroll
    for (int j = 0; j < 4; ++j)
#pragma unroll
        for (int i = 0; i < 4; ++i)
            acc[j][i] = (f32x4){0.f, 0.f, 0.f, 0.f};

    STAGE6(0, 0);
    STAGE6(1, 1);
    WAIT_VM(4);
    __builtin_amdgcn_s_barrier();

    const int KS = DIM / 32;   // 16 K-steps
#pragma unroll
    for (int t = 0; t < KS; ++t) {
        const int cb = t % 3;
        if (t + 2 < KS) STAGE6((t + 2) % 3, t + 2);
        f16x8 af[4], bf[4];
#pragma unroll
        for (int i = 0; i < 4; ++i)
            af[i] = *(const f16x8*)&As[cb][wr * 64 + i * 16 + c16][(g ^ rsw) * 8];
#pragma unroll
        for (int j = 0; j < 4; ++j)
            bf[j] = *(const f16x8*)&Bs[cb][wc * 64 + j * 16 + c16][(g ^ rsw) * 8];
        __builtin_amdgcn_s_setprio(1);
#pragma unroll
        for (int j = 0; j < 4; ++j)
#pragma unroll
            for (int i = 0; i < 4; ++i)
                acc[j][i] = __builtin_amdgcn_mfma_f32_16x16x32_f16(bf[j], af[i], acc[j][i], 0, 0, 0);
        __builtin_amdgcn_s_setprio(0);
        WAIT_LGKM;
        __builtin_amdgcn_sched_barrier(0);
        if (t + 2 < KS) {
            WAIT_VM(4);
        } else if (t + 1 < KS) {
            WAIT_VM(0);
        }
        if (t + 1 < KS) __builtin_amdgcn_s_barrier();
    }
#undef STAGE6

#pragma unroll
    for (int i = 0; i < 4; ++i) {
        const int m = m0 + wr * 64 + i * 16 + c16;
#pragma unroll
        for (int j = 0; j < 4; ++j) {
            const int n = n0 + wc * 64 + j * 16 + g * 4;
            f32x4 v = acc[j][i];
            const f32x4 b4 = *(const f32x4*)&bias[n];
            v += b4;
            float4 o = { v[0], v[1], v[2], v[3] };
            *(float4*)(outp + (size_t)m * DIM + n) = o;
        }
    }
}

// ---------------- fused window attention v5: table-first + swizzled 32KB Ps ----------------
// v2 with (a) table-first ordering (cbv->St before qf/kf; measured VGPR 60 in r16's
// fused variant) and (b) Ps stride 72 -> 64 via 16B-chunk XOR swizzle (chunk ^= row&7,
// <=2-way aliasing = free): LDS 36.9KB -> 32KB exactly -> 5 blocks/CU = 20 waves/CU
// (+25% TLP for this latency-bound kernel). Waves stay independent (no __syncthreads).
__global__ __launch_bounds__(256) void attn_kernel(const f16* __restrict__ qw,
                                                   const f16* __restrict__ kw,
                                                   const f16* __restrict__ vt,
                                                   const f16* __restrict__ comb2,
                                                   f16* __restrict__ aout) {
    __shared__ __align__(16) f16 Ps[4][64][64];   // 32768 B

    const int wv = threadIdx.x >> 6;
    const int l = threadIdx.x & 63;
    const int f = blockIdx.x;
    const int work = (f & 7) * (gridDim.x >> 3) + (f >> 3);
    const int bid = work * 4 + wv;
    const int b = bid >> 4, h = bid & 15;
    const int w = b & (NWIN - 1);
    const int g = l >> 4, c16 = l & 15;
    const size_t qkbase = (size_t)bid * (NTOK * HD);
    const size_t vbase = (size_t)bid * (HD * VTS);

    const f16x8 z8 = {};

    // table first (keeps peak VGPR low: St init before qf/kf live)
    const f16* cb = comb2 + (((size_t)(w * NH + h) * 64 + l) << 6);
    f32x4 St[4][4];   // St[i][j]: i = k-tile, j = q-tile
    {
        f16x8 cbv[8];
#pragma unroll
        for (int k = 0; k < 8; ++k) cbv[k] = *(const f16x8*)(cb + k * 8);
#pragma unroll
        for (int i = 0; i < 4; ++i)
#pragma unroll
            for (int j = 0; j < 4; ++j) {
                const int e = i * 16 + j * 4;
#pragma unroll
                for (int r = 0; r < 4; ++r)
                    St[i][j][r] = (float)cbv[(e + r) >> 3][(e + r) & 7];
            }
    }
    {
        f16x8 qf[4], kf[4];
#pragma unroll
        for (int t = 0; t < 4; ++t) {
            int row = t * 16 + c16;
            f16x8 q = z8, k = z8;
            if (row < NTOK) {
                q = *(const f16x8*)(qw + qkbase + row * HD + g * 8);
                k = *(const f16x8*)(kw + qkbase + row * HD + g * 8);
            }
            qf[t] = q; kf[t] = k;
        }
#pragma unroll
        for (int i = 0; i < 4; ++i)
#pragma unroll
            for (int j = 0; j < 4; ++j)
                St[i][j] = __builtin_amdgcn_mfma_f32_16x16x32_f16(kf[i], qf[j], St[i][j], 0, 0, 0);
    }

    // prefetch V^T fragments (latency hides under softmax)
    f16x8 vfp[2][2];
#pragma unroll
    for (int c = 0; c < 2; ++c) {
        int tcol = c * 32 + g * 8;
#pragma unroll
        for (int td = 0; td < 2; ++td) {
            f16x8 vv = z8;
            if (tcol < VTS)
                vv = *(const f16x8*)(vt + vbase + (size_t)(td * 16 + c16) * VTS + tcol);
            vfp[c][td] = vv;
        }
    }

    // in-lane softmax per q-tile j
    float inv[4];
#pragma unroll
    for (int j = 0; j < 4; ++j) {
        float m = St[0][j][0];
#pragma unroll
        for (int i = 0; i < 4; ++i)
#pragma unroll
            for (int r = 0; r < 4; ++r) m = fmaxf(m, St[i][j][r]);
        m = fmaxf(m, __shfl_xor(m, 16, 64));
        m = fmaxf(m, __shfl_xor(m, 32, 64));
        float s = 0.f;
#pragma unroll
        for (int i = 0; i < 4; ++i)
#pragma unroll
            for (int r = 0; r < 4; ++r) {
                float p = __expf(St[i][j][r] - m);
                St[i][j][r] = p;
                s += p;
            }
        s += __shfl_xor(s, 16, 64);
        s += __shfl_xor(s, 32, 64);
        inv[j] = 1.f / s;
    }

    // pack P (unnormalized) into swizzled wave-private Ps slice:
    // byte addr(row, col) = row*128 + ((col>>3 ^ (row&7))<<4) + (col&7)*2
#pragma unroll
    for (int j = 0; j < 4; ++j) {
        const int q = j * 16 + c16;
        char* prow = (char*)&Ps[wv][q][0];
#pragma unroll
        for (int i = 0; i < 4; ++i) {
            fp16x2 u0 = __builtin_amdgcn_cvt_pkrtz(St[i][j][0], St[i][j][1]);
            fp16x2 u1 = __builtin_amdgcn_cvt_pkrtz(St[i][j][2], St[i][j][3]);
            const int chunk = (i * 2 + (g >> 1)) ^ (q & 7);      // col = i*16+4g
            char* base = prow + chunk * 16 + (g & 1) * 8;
            *(fp16x2*)(base)     = u0;
            *(fp16x2*)(base + 4) = u1;
        }
    }
    WAIT_LGKM;   // wave-private region: write->read ordering only

    f32x4 O2[2][4];
    const f32x4 zf = (f32x4){0.f, 0.f, 0.f, 0.f};
#pragma unroll
    for (int td = 0; td < 2; ++td)
#pragma unroll
        for (int ti = 0; ti < 4; ++ti) O2[td][ti] = zf;
#pragma unroll
    for (int c = 0; c < 2; ++c) {
        f16x8 pf[4];
#pragma unroll
        for (int ti = 0; ti < 4; ++ti) {
            const int row = ti * 16 + c16;
            const int chunk = (c * 4 + g) ^ (row & 7);           // col = c*32+g*8
            pf[ti] = *(const f16x8*)((char*)&Ps[wv][row][0] + chunk * 16);
        }
#pragma unroll
        for (int td = 0; td < 2; ++td)
#pragma unroll
            for (int ti = 0; ti < 4; ++ti)
                O2[td][ti] = __builtin_amdgcn_mfma_f32_16x16x32_f16(vfp[c][td], pf[ti], O2[td][ti], 0, 0, 0);
    }

#pragma unroll
    for (int ti = 0; ti < 4; ++ti) {
        int tok = ti * 16 + c16;
        if (tok < NTOK) {
            size_t ob = ((size_t)(b * NTOK + tok)) * DIM + h * HD;
#pragma unroll
            for (int td = 0; td < 2; ++td) {
                f32x4 v = O2[td][ti];
                float iv = inv[ti];
                f16x4 o = { (f16)(v[0] * iv), (f16)(v[1] * iv),
                            (f16)(v[2] * iv), (f16)(v[3] * iv) };
                *(f16x4*)(aout + ob + td * 16 + g * 4) = o;
            }
        }
    }
}

// ---------------- launcher ----------------
extern "C" void kernel_launch(void* const* d_in, const int* in_sizes, int n_in,
                              void* d_out, int out_size, void* d_ws, size_t ws_size,
                              hipStream_t stream) {
    const float* x      = (const float*)d_in[0];
    const float* mask   = (const float*)d_in[1];
    const float* rpb    = (const float*)d_in[2];
    const float* qkv_w  = (const float*)d_in[3];
    const float* qkv_b  = (const float*)d_in[4];
    const float* proj_w = (const float*)d_in[5];
    const float* proj_b = (const float*)d_in[6];
    float* out = (float*)d_out;

    char* ws = (char*)d_ws;
    size_t o = 0;
    f16* x16   = (f16*)(ws + o); o += (size_t)MTOT * DIM * 2;
    f16* w16   = (f16*)(ws + o); o += (size_t)1536 * 512 * 2;
    f16* pw16  = (f16*)(ws + o); o += (size_t)512 * 512 * 2;
    f16* qws   = (f16*)(ws + o); o += (size_t)NB * NH * NTOK * HD * 2;
    f16* kws   = (f16*)(ws + o); o += (size_t)NB * NH * NTOK * HD * 2;
    f16* vtws  = (f16*)(ws + o); o += (size_t)NB * NH * HD * VTS * 2;
    f16* cb2   = (f16*)(ws + o);
    f16* aout = x16;   // x16 dead after QKV GEMM

    // all converts + comb2T in one launch
    prep_kernel<<<dim3(16384 + 2048 + 768 + 256), dim3(256), 0, stream>>>(
        rpb, mask, cb2, qkv_w, w16, proj_w, pw16, x, x16);

    // QKV: 392 m-tiles x 6 n-tiles = 2352 blocks (divisible by 8)
    gemm256<6><<<dim3((MTOT / 256) * 6), dim3(512), 0, stream>>>(
        x16, w16, qkv_b, qws, kws, vtws);

    attn_kernel<<<dim3(NB * NH / 4), dim3(256), 0, stream>>>(qws, kws, vtws, cb2, aout);

    // proj: 784 x 4 = 3136 blocks, 128^2 tile, 3 blocks/CU
    gemm128<<<dim3((MTOT / 128) * 4), dim3(256), 0, stream>>>(
        aout, pw16, proj_b, out);
}